// Round 4
// baseline (335.851 us; speedup 1.0000x reference)
//
#include <hip/hip_runtime.h>

// ---------------------------------------------------------------------------
// SelfAttentionBlock: B=4, N=2048, D=1024.
//   QKV = X @ Wqkv^T                   (8192x1024)@(3072x1024)^T   [core A]
//   E_b = exp(Q_b @ K_b^T * 0.125)     bf16 + row-sum L (atomic)   [core A, fused]
//   V''_b = Wout @ V_b^T               (1024x2048) per batch       [core A, fused]
//   out_b = (E_b @ V''_b^T) / L + b    fp32                        [128² R1 core]
// R11: core A = 256x128 block tile, 4 waves, WAVE TILE 128x64 (acc[4][2]).
// Per wave per K-tile: 24 ds_read_b128 -> 32 MFMA = 42.7 FLOP/LDS-byte
// (was 64x64 wave tile: 16 reads -> 16 MFMA = 32 FLOP/B, LDS-read-bound).
// 1-phase sync kept (R3 proved explicit dbuf neutral: TLP already hides
// staging; dbuf cost a resident block). 48 KiB LDS -> 2 blocks/CU.
// ---------------------------------------------------------------------------

typedef __bf16 bf16;
typedef __attribute__((ext_vector_type(8))) __bf16 bf16x8;
typedef __attribute__((ext_vector_type(4))) __bf16 bf16x4;
typedef __attribute__((ext_vector_type(16))) float f32x16;

#define BATCH 4
#define NTOK  2048
#define DIM   1024
#define MROWS (BATCH * NTOK)   // 8192
#define QKVC  (3 * DIM)        // 3072

__device__ __forceinline__ void async16(const bf16* g, bf16* l) {
  __builtin_amdgcn_global_load_lds(
      (const __attribute__((address_space(1))) void*)g,
      (__attribute__((address_space(3))) void*)l, 16, 0, 0);
}

// ---------------------------------------------------------------------------
// prep: three fp32->bf16 converts + L zero
// ---------------------------------------------------------------------------
__device__ __forceinline__ void cvt4(const float* in, bf16* out, int i4) {
  float4 f = *(const float4*)(in + i4 * 4);
  bf16x4 o;
  o.x = (bf16)f.x; o.y = (bf16)f.y; o.z = (bf16)f.z; o.w = (bf16)f.w;
  *(bf16x4*)(out + i4 * 4) = o;
}

__global__ void prep(const float* __restrict__ x, const float* __restrict__ wqkv,
                     const float* __restrict__ wout,
                     bf16* __restrict__ Xbf, bf16* __restrict__ Wqkvb,
                     bf16* __restrict__ Woutb, float* __restrict__ L) {
  const int nx = MROWS * DIM / 4, nq = QKVC * DIM / 4, nw = DIM * DIM / 4;
  const int nl = BATCH * NTOK / 4;
  int i = blockIdx.x * blockDim.x + threadIdx.x;
  if (i < nx) cvt4(x, Xbf, i);
  else if (i < nx + nq) cvt4(wqkv, Wqkvb, i - nx);
  else if (i < nx + nq + nw) cvt4(wout, Woutb, i - nx - nq);
  else if (i < nx + nq + nw + nl) {
    float4 z = {0.f, 0.f, 0.f, 0.f};
    *(float4*)(L + (i - nx - nq - nw) * 4) = z;
  }
}

// ===========================================================================
// Core A: 256(M) x 128(N) block, BK=64, 4 waves as 2(M)x2(N), wave 128x64 =
// 4x2 of 32x32x16 MFMA. acc[4][2] (128 VGPR).
// LDS: As[256][64] (32 KB) + Bs[128][64] (16 KB) = 48 KB, single buffer.
// Row = 8 chunks of 8 bf16; physical slot c of row r holds global chunk
// c^(r&7); staging tid->row=tid>>3 (+32*seg), slot=tid&7, swizzle applied to
// the GLOBAL source column so LDS dst stays linear (tid*16 per seg shot).
// A-frag: A[m=lane&31][k=8*(lane>>5)+e]; C/D: col=lane&31,
// row=(reg&3)+8*(reg>>2)+4*(lane>>5)  (verified layout, carried over).
// ===========================================================================
struct CoreA {
  const bf16 *ga[8], *gb[4];
  int sA[8], sB[4];
  int wm, wn, l31, half;
};

__device__ __forceinline__ CoreA coreA_setup(const bf16* A, const bf16* Bm,
                                             int lda, int ldb,
                                             long rowA, long rowB) {
  CoreA g;
  const int tid = threadIdx.x;
  const int wave = tid >> 6, lane = tid & 63;
  g.wm = (wave >> 1) * 128;          // wave-row: 0 or 128
  g.wn = (wave & 1) * 64;            // wave-col: 0 or 64
  g.l31 = lane & 31;
  g.half = lane >> 5;
  const int srow = tid >> 3;               // 0..31
  const int sc   = tid & 7;                // physical slot
  const int scol = (sc ^ (srow & 7)) << 3; // swizzled global chunk * 8
#pragma unroll
  for (int seg = 0; seg < 8; ++seg) {
    g.ga[seg] = A + (rowA + srow + 32 * seg) * (long)lda + scol;
    g.sA[seg] = (srow + 32 * seg) * 64 + sc * 8;
  }
#pragma unroll
  for (int seg = 0; seg < 4; ++seg) {
    g.gb[seg] = Bm + (rowB + srow + 32 * seg) * (long)ldb + scol;
    g.sB[seg] = (srow + 32 * seg) * 64 + sc * 8;
  }
  return g;
}

__device__ __forceinline__ void coreA_kloop(const CoreA& g, int K,
                                            bf16* As, bf16* Bs,
                                            f32x16 acc[4][2]) {
  const int sw = g.l31 & 7;
  for (int kt = 0; kt < K; kt += 64) {
#pragma unroll
    for (int seg = 0; seg < 8; ++seg) async16(g.ga[seg] + kt, As + g.sA[seg]);
#pragma unroll
    for (int seg = 0; seg < 4; ++seg) async16(g.gb[seg] + kt, Bs + g.sB[seg]);
    __syncthreads();

    bf16x8 af[4][4], bfm[2][4];
#pragma unroll
    for (int ti = 0; ti < 4; ++ti)
#pragma unroll
      for (int s = 0; s < 4; ++s)
        af[ti][s] = *(const bf16x8*)&As[(g.wm + ti * 32 + g.l31) * 64 + ((s * 2 + g.half) ^ sw) * 8];
#pragma unroll
    for (int tj = 0; tj < 2; ++tj)
#pragma unroll
      for (int s = 0; s < 4; ++s)
        bfm[tj][s] = *(const bf16x8*)&Bs[(g.wn + tj * 32 + g.l31) * 64 + ((s * 2 + g.half) ^ sw) * 8];

#pragma unroll
    for (int s = 0; s < 4; ++s)
#pragma unroll
      for (int ti = 0; ti < 4; ++ti)
#pragma unroll
        for (int tj = 0; tj < 2; ++tj)
          acc[ti][tj] = __builtin_amdgcn_mfma_f32_32x32x16_bf16(
              af[ti][s], bfm[tj][s], acc[ti][tj], 0, 0, 0);

    __syncthreads();
  }
}

// ---- QKV = X @ Wqkv^T (core A), bf16 out -----------------------------------
__launch_bounds__(256)
__global__ void gemm_qkv(const bf16* __restrict__ Xb, const bf16* __restrict__ Wq,
                         bf16* __restrict__ QKV) {
  __shared__ alignas(16) bf16 As[256 * 64];
  __shared__ alignas(16) bf16 Bs[128 * 64];
  const long rowA = (long)blockIdx.y * 256;
  const long rowB = (long)blockIdx.x * 128;
  CoreA g = coreA_setup(Xb, Wq, DIM, DIM, rowA, rowB);
  f32x16 acc[4][2] = {};
  coreA_kloop(g, DIM, As, Bs, acc);
#pragma unroll
  for (int ti = 0; ti < 4; ++ti)
#pragma unroll
    for (int tj = 0; tj < 2; ++tj) {
      const long col = rowB + g.wn + tj * 32 + g.l31;
#pragma unroll
      for (int r = 0; r < 16; ++r) {
        const long row = rowA + g.wm + ti * 32 + (r & 3) + 8 * (r >> 2) + 4 * g.half;
        QKV[row * (long)QKVC + col] = (bf16)acc[ti][tj][r];
      }
    }
}

// ---- fused (core A): z<4 -> E_b = exp(QK^T/8)+L ; z>=4 -> V'' = Wout@V^T ---
__launch_bounds__(256)
__global__ void gemm_sv(const bf16* __restrict__ QKV, const bf16* __restrict__ Wout,
                        bf16* __restrict__ E, bf16* __restrict__ Vpp,
                        float* __restrict__ Lroot) {
  __shared__ alignas(16) bf16 As[256 * 64];
  __shared__ alignas(16) bf16 Bs[128 * 64];
  const int z = blockIdx.z;
  if (z < 4) {
    // ---- E-GEMM: A=Q, B=K rows of QKV batch z; M=N=2048 ----
    const bf16* A  = QKV + (long)z * NTOK * QKVC;
    const bf16* Bm = A + DIM;
    const long rowA = (long)blockIdx.y * 256;
    const long rowB = (long)blockIdx.x * 128;
    CoreA g = coreA_setup(A, Bm, QKVC, QKVC, rowA, rowB);
    f32x16 acc[4][2] = {};
    coreA_kloop(g, DIM, As, Bs, acc);

    bf16* C = E + (long)z * NTOK * NTOK;
    float* L = Lroot + (long)z * NTOK;
#pragma unroll
    for (int ti = 0; ti < 4; ++ti) {
#pragma unroll
      for (int r = 0; r < 16; ++r) {
        const long row = rowA + g.wm + ti * 32 + (r & 3) + 8 * (r >> 2) + 4 * g.half;
        float psum = 0.f;
#pragma unroll
        for (int tj = 0; tj < 2; ++tj) {
          const long col = rowB + g.wn + tj * 32 + g.l31;
          float e = __expf(acc[ti][tj][r] * 0.125f);
          bf16 eb = (bf16)e;
          C[row * (long)NTOK + col] = eb;
          psum += (float)eb;   // sum what downstream consumes
        }
#pragma unroll
        for (int off = 16; off >= 1; off >>= 1) psum += __shfl_xor(psum, off, 64);
        if (g.l31 == 0) atomicAdd(&L[row], psum);
      }
    }
  } else {
    if (blockIdx.y >= 4) return;   // V'' has 1024 rows = 4 tiles of 256
    const int b = z - 4;
    const bf16* Bm = QKV + (long)b * NTOK * QKVC + 2 * DIM;
    const long rowA = (long)blockIdx.y * 256;
    const long rowB = (long)blockIdx.x * 128;
    CoreA g = coreA_setup(Wout, Bm, DIM, QKVC, rowA, rowB);
    f32x16 acc[4][2] = {};
    coreA_kloop(g, DIM, As, Bs, acc);

    bf16* C = Vpp + (long)b * DIM * NTOK;
#pragma unroll
    for (int ti = 0; ti < 4; ++ti)
#pragma unroll
      for (int tj = 0; tj < 2; ++tj) {
        const long col = rowB + g.wn + tj * 32 + g.l31;
#pragma unroll
        for (int r = 0; r < 16; ++r) {
          const long row = rowA + g.wm + ti * 32 + (r & 3) + 8 * (r >> 2) + 4 * g.half;
          C[row * (long)NTOK + col] = (bf16)acc[ti][tj][r];
        }
      }
  }
}

// ===========================================================================
// 128² R1 core (proven) for the out-GEMM. 4 waves 2x2, wave 64x64, 1-phase.
// ===========================================================================
struct GemmCore {
  const bf16 *ga[4], *gb[4];
  int sIdx[4];
  int wm, wn, l31, half;
};

__device__ __forceinline__ GemmCore gemm_setup(const bf16* A, const bf16* Bm,
                                               int lda, int ldb,
                                               long rowA, long rowB) {
  GemmCore g;
  const int tid = threadIdx.x;
  const int wave = tid >> 6, lane = tid & 63;
  g.wm = (wave >> 1) << 6;
  g.wn = (wave & 1) << 6;
  g.l31 = lane & 31;
  g.half = lane >> 5;
  const int srow = tid >> 3;
  const int sc   = tid & 7;
  const int scol = (sc ^ (srow & 7)) << 3;
#pragma unroll
  for (int seg = 0; seg < 4; ++seg) {
    g.ga[seg] = A  + (rowA + srow + 32 * seg) * (long)lda + scol;
    g.gb[seg] = Bm + (rowB + srow + 32 * seg) * (long)ldb + scol;
    g.sIdx[seg] = (srow + 32 * seg) * 64 + sc * 8;
  }
  return g;
}

__device__ __forceinline__ void gemm_kloop(const GemmCore& g, int K,
                                           bf16* As, bf16* Bs, f32x16 acc[2][2]) {
  const int sw = g.l31 & 7;
  for (int kt = 0; kt < K; kt += 64) {
#pragma unroll
    for (int seg = 0; seg < 4; ++seg) {
      async16(g.ga[seg] + kt, As + g.sIdx[seg]);
      async16(g.gb[seg] + kt, Bs + g.sIdx[seg]);
    }
    __syncthreads();

    bf16x8 af[2][4], bfm[2][4];
#pragma unroll
    for (int ti = 0; ti < 2; ++ti)
#pragma unroll
      for (int s = 0; s < 4; ++s)
        af[ti][s] = *(const bf16x8*)&As[(g.wm + ti * 32 + g.l31) * 64 + ((s * 2 + g.half) ^ sw) * 8];
#pragma unroll
    for (int tj = 0; tj < 2; ++tj)
#pragma unroll
      for (int s = 0; s < 4; ++s)
        bfm[tj][s] = *(const bf16x8*)&Bs[(g.wn + tj * 32 + g.l31) * 64 + ((s * 2 + g.half) ^ sw) * 8];

#pragma unroll
    for (int s = 0; s < 4; ++s)
#pragma unroll
      for (int ti = 0; ti < 2; ++ti)
#pragma unroll
        for (int tj = 0; tj < 2; ++tj)
          acc[ti][tj] = __builtin_amdgcn_mfma_f32_32x32x16_bf16(
              af[ti][s], bfm[tj][s], acc[ti][tj], 0, 0, 0);

    __syncthreads();
  }
}

// out_b = (E_b @ V''_b^T)/L + bias  (fp32 store)
__launch_bounds__(256)
__global__ void gemm_out(const bf16* __restrict__ Eroot, const bf16* __restrict__ Vroot,
                         float* __restrict__ Croot, const float* __restrict__ bias,
                         const float* __restrict__ Lroot) {
  const bf16* A  = Eroot + (long)blockIdx.z * NTOK * NTOK;
  const bf16* Bm = Vroot + (long)blockIdx.z * DIM * NTOK;
  __shared__ alignas(16) bf16 As[128 * 64];
  __shared__ alignas(16) bf16 Bs[128 * 64];

  const long rowA = (long)blockIdx.y * 128;
  const long rowB = (long)blockIdx.x * 128;
  GemmCore g = gemm_setup(A, Bm, NTOK, NTOK, rowA, rowB);

  f32x16 acc[2][2] = {};
  gemm_kloop(g, NTOK, As, Bs, acc);

  float* C = Croot + (long)blockIdx.z * NTOK * DIM;
  const float* L = Lroot + (long)blockIdx.z * NTOK;
#pragma unroll
  for (int ti = 0; ti < 2; ++ti) {
#pragma unroll
    for (int r = 0; r < 16; ++r) {
      const long row = rowA + g.wm + ti * 32 + (r & 3) + 8 * (r >> 2) + 4 * g.half;
      const float inv = 1.0f / L[row];
#pragma unroll
      for (int tj = 0; tj < 2; ++tj) {
        const long col = rowB + g.wn + tj * 32 + g.l31;
        C[row * (long)DIM + col] = acc[ti][tj][r] * inv + bias[col];
      }
    }
  }
}

// ---------------------------------------------------------------------------
extern "C" void kernel_launch(void* const* d_in, const int* in_sizes, int n_in,
                              void* d_out, int out_size, void* d_ws, size_t ws_size,
                              hipStream_t stream) {
  const float* x      = (const float*)d_in[0];   // (4,2048,1024)
  const float* w_qkv  = (const float*)d_in[1];   // (3072,1024)
  const float* w_out  = (const float*)d_in[2];   // (1024,1024)
  const float* b_out  = (const float*)d_in[3];   // (1024,)
  float* out = (float*)d_out;                    // (4,2048,1024) fp32

  // workspace layout (bytes) — total ~120 MiB
  char* w = (char*)d_ws;
  bf16*  Xbf   = (bf16*)(w);                          // 8192*1024*2   = 16 MiB
  bf16*  Wqkvb = (bf16*)(w + 16777216);               // 3072*1024*2   =  6 MiB
  bf16*  Woutb = (bf16*)(w + 23068672);               // 1024*1024*2   =  2 MiB
  bf16*  QKV   = (bf16*)(w + 25165824);               // 8192*3072*2   = 48 MiB
  bf16*  E     = (bf16*)(w + 75497472);               // 4*2048*2048*2 = 32 MiB
  bf16*  Vpp   = (bf16*)(w + 109051904);              // 4*1024*2048*2 = 16 MiB
  float* L     = (float*)(w + 125829120);             // 4*2048*4      = 32 KiB

  // 1) one prep dispatch: converts + L zero
  {
    const int n4 = MROWS * DIM / 4 + QKVC * DIM / 4 + DIM * DIM / 4 + BATCH * NTOK / 4;
    prep<<<(n4 + 255) / 256, 256, 0, stream>>>(x, w_qkv, w_out, Xbf, Wqkvb, Woutb, L);
  }

  // 2) QKV = X @ Wqkv^T -> bf16 (8192 x 3072), core A: 32x24 = 768 blocks
  gemm_qkv<<<dim3(QKVC / 128, MROWS / 256, 1), 256, 0, stream>>>(Xbf, Wqkvb, QKV);

  // 3) fused: E_b = exp(Q_b@K_b^T/8) + L row-sums AND V''_b = Wout @ V_b^T
  //    core A: z<4 E uses 8x16; z>=4 V'' uses y<4 (768 active blocks)
  gemm_sv<<<dim3(NTOK / 128, NTOK / 256, 2 * BATCH), 256, 0, stream>>>(
      QKV, Woutb, E, Vpp, L);

  // 4) out_b = (E_b @ V''_b^T) / L + b_out -> fp32, 128² core, 512 blocks
  gemm_out<<<dim3(DIM / 128, NTOK / 128, BATCH), 256, 0, stream>>>(
      E, Vpp, out, b_out, L);
}

// Round 5
// 274.111 us; speedup vs baseline: 1.2252x; 1.2252x over previous
//
#include <hip/hip_runtime.h>

// ---------------------------------------------------------------------------
// SelfAttentionBlock: B=4, N=2048, D=1024.
//   QKV = X @ Wqkv^T                   (8192x1024)@(3072x1024)^T
//   E_b = exp(Q_b @ K_b^T * 0.125)     bf16 + row-sum L (atomic)
//   V''_b = Wout @ V_b^T               (1024x2048) per batch (fused in sv)
//   out_b = (E_b @ V''_b^T) / L + b    fp32
// R12: core = R1 proven 128x128 / BK=64 / 1-phase / 32 KiB / ~80 VGPR
// (max residency: R1/R3/R11 showed perf tracks occupancy 27/19.5/10.7% ->
// 76/80.6/113 us; latency-bound, lives on TLP — never pay registers or LDS).
// NEW: T1 XCD-aware swizzle on 1D grids (all %8==0, bijective) + exact block
// counts (kills 512 dead V'' blocks). Targets the 1.8x HBM over-fetch
// (90 MB vs ~50 compulsory) from neighbor tiles landing on different XCD L2s.
// ---------------------------------------------------------------------------

typedef __bf16 bf16;
typedef __attribute__((ext_vector_type(8))) __bf16 bf16x8;
typedef __attribute__((ext_vector_type(4))) __bf16 bf16x4;
typedef __attribute__((ext_vector_type(16))) float f32x16;

#define BATCH 4
#define NTOK  2048
#define DIM   1024
#define MROWS (BATCH * NTOK)   // 8192
#define QKVC  (3 * DIM)        // 3072

__device__ __forceinline__ void async16(const bf16* g, bf16* l) {
  __builtin_amdgcn_global_load_lds(
      (const __attribute__((address_space(1))) void*)g,
      (__attribute__((address_space(3))) void*)l, 16, 0, 0);
}

// ---------------------------------------------------------------------------
// prep: three fp32->bf16 converts + L zero
// ---------------------------------------------------------------------------
__device__ __forceinline__ void cvt4(const float* in, bf16* out, int i4) {
  float4 f = *(const float4*)(in + i4 * 4);
  bf16x4 o;
  o.x = (bf16)f.x; o.y = (bf16)f.y; o.z = (bf16)f.z; o.w = (bf16)f.w;
  *(bf16x4*)(out + i4 * 4) = o;
}

__global__ void prep(const float* __restrict__ x, const float* __restrict__ wqkv,
                     const float* __restrict__ wout,
                     bf16* __restrict__ Xbf, bf16* __restrict__ Wqkvb,
                     bf16* __restrict__ Woutb, float* __restrict__ L) {
  const int nx = MROWS * DIM / 4, nq = QKVC * DIM / 4, nw = DIM * DIM / 4;
  const int nl = BATCH * NTOK / 4;
  int i = blockIdx.x * blockDim.x + threadIdx.x;
  if (i < nx) cvt4(x, Xbf, i);
  else if (i < nx + nq) cvt4(wqkv, Wqkvb, i - nx);
  else if (i < nx + nq + nw) cvt4(wout, Woutb, i - nx - nq);
  else if (i < nx + nq + nw + nl) {
    float4 z = {0.f, 0.f, 0.f, 0.f};
    *(float4*)(L + (i - nx - nq - nw) * 4) = z;
  }
}

// ---------------------------------------------------------------------------
// GEMM core (R1 proven). C[i][j] = sum_k A[i][k] * B[j][k]. BK=64.
// 32x32x16 MFMA, 4 waves 2x2, wave 64x64 = 2x2 of 32x32.
// A-frag: A[m=lane&31][k=8*(lane>>5)+e]. C/D: col=lane&31,
// row=(reg&3)+8*(reg>>2)+4*(lane>>5).
// LDS tile [128 rows][64 k]; slot c of row r holds global chunk c^(r&7);
// staging tid->row=tid>>3 (+32*seg), slot=tid&7; swizzle applied on GLOBAL
// source col so global_load_lds dst stays linear (tid*16).
// ---------------------------------------------------------------------------
struct GemmCore {
  const bf16 *ga[4], *gb[4];
  int sIdx[4];
  int wm, wn, l31, half;
};

__device__ __forceinline__ GemmCore gemm_setup(const bf16* A, const bf16* Bm,
                                               int lda, int ldb,
                                               long rowA, long rowB) {
  GemmCore g;
  const int tid = threadIdx.x;
  const int wave = tid >> 6, lane = tid & 63;
  g.wm = (wave >> 1) << 6;
  g.wn = (wave & 1) << 6;
  g.l31 = lane & 31;
  g.half = lane >> 5;
  const int srow = tid >> 3;               // 0..31
  const int sc   = tid & 7;                // physical slot
  const int scol = (sc ^ (srow & 7)) << 3; // swizzled global chunk * 8
#pragma unroll
  for (int seg = 0; seg < 4; ++seg) {
    g.ga[seg] = A  + (rowA + srow + 32 * seg) * (long)lda + scol;
    g.gb[seg] = Bm + (rowB + srow + 32 * seg) * (long)ldb + scol;
    g.sIdx[seg] = (srow + 32 * seg) * 64 + sc * 8;
  }
  return g;
}

__device__ __forceinline__ void gemm_kloop(const GemmCore& g, int K,
                                           bf16* As, bf16* Bs, f32x16 acc[2][2]) {
  const int sw = g.l31 & 7;
  for (int kt = 0; kt < K; kt += 64) {
#pragma unroll
    for (int seg = 0; seg < 4; ++seg) {
      async16(g.ga[seg] + kt, As + g.sIdx[seg]);
      async16(g.gb[seg] + kt, Bs + g.sIdx[seg]);
    }
    __syncthreads();

    bf16x8 af[2][4], bfm[2][4];
#pragma unroll
    for (int ti = 0; ti < 2; ++ti)
#pragma unroll
      for (int s = 0; s < 4; ++s)
        af[ti][s] = *(const bf16x8*)&As[(g.wm + ti * 32 + g.l31) * 64 + ((s * 2 + g.half) ^ sw) * 8];
#pragma unroll
    for (int tj = 0; tj < 2; ++tj)
#pragma unroll
      for (int s = 0; s < 4; ++s)
        bfm[tj][s] = *(const bf16x8*)&Bs[(g.wn + tj * 32 + g.l31) * 64 + ((s * 2 + g.half) ^ sw) * 8];

#pragma unroll
    for (int s = 0; s < 4; ++s)
#pragma unroll
      for (int ti = 0; ti < 2; ++ti)
#pragma unroll
        for (int tj = 0; tj < 2; ++tj)
          acc[ti][tj] = __builtin_amdgcn_mfma_f32_32x32x16_bf16(
              af[ti][s], bfm[tj][s], acc[ti][tj], 0, 0, 0);

    __syncthreads();
  }
}

// ---------------------------------------------------------------------------
// QKV = X @ Wqkv^T. 1D grid 1536 = 64(y) x 24(x), x-major; XCD swizzle.
// ---------------------------------------------------------------------------
__launch_bounds__(256)
__global__ void gemm_qkv(const bf16* __restrict__ Xb, const bf16* __restrict__ Wq,
                         bf16* __restrict__ QKV) {
  __shared__ alignas(16) bf16 As[128 * 64];
  __shared__ alignas(16) bf16 Bs[128 * 64];
  int wg = blockIdx.x;
  wg = (wg & 7) * 192 + (wg >> 3);        // 1536/8 = 192 per XCD, bijective
  const int by = wg / 24, bx = wg - by * 24;

  const long rowA = (long)by * 128;
  const long rowB = (long)bx * 128;
  GemmCore g = gemm_setup(Xb, Wq, DIM, DIM, rowA, rowB);
  f32x16 acc[2][2] = {};
  gemm_kloop(g, DIM, As, Bs, acc);

#pragma unroll
  for (int ti = 0; ti < 2; ++ti)
#pragma unroll
    for (int tj = 0; tj < 2; ++tj) {
      const long col = rowB + g.wn + tj * 32 + g.l31;
#pragma unroll
      for (int r = 0; r < 16; ++r) {
        const long row = rowA + g.wm + ti * 32 + (r & 3) + 8 * (r >> 2) + 4 * g.half;
        QKV[row * (long)QKVC + col] = (bf16)acc[ti][tj][r];
      }
    }
}

// ---------------------------------------------------------------------------
// Fused sv. 1D grid 1536 (exact): wg<1024 -> E-block (z=wg>>8, 16x16 tiles,
// x-major); else V''-block (b=(wg-1024)>>7, 8(y) x 16(x) tiles). XCD swizzle.
// ---------------------------------------------------------------------------
__launch_bounds__(256)
__global__ void gemm_sv(const bf16* __restrict__ QKV, const bf16* __restrict__ Wout,
                        bf16* __restrict__ E, bf16* __restrict__ Vpp,
                        float* __restrict__ Lroot) {
  __shared__ alignas(16) bf16 As[128 * 64];
  __shared__ alignas(16) bf16 Bs[128 * 64];
  int wg = blockIdx.x;
  wg = (wg & 7) * 192 + (wg >> 3);        // bijective XCD swizzle

  if (wg < 1024) {
    // ---- E-GEMM: A=Q, B=K rows of QKV batch z ----
    const int z = wg >> 8, rem = wg & 255;
    const int by = rem >> 4, bx = rem & 15;
    const bf16* A  = QKV + (long)z * NTOK * QKVC;
    const bf16* Bm = A + DIM;
    const long rowA = (long)by * 128;
    const long rowB = (long)bx * 128;
    GemmCore g = gemm_setup(A, Bm, QKVC, QKVC, rowA, rowB);
    f32x16 acc[2][2] = {};
    gemm_kloop(g, DIM, As, Bs, acc);

    bf16* C = E + (long)z * NTOK * NTOK;
    float* L = Lroot + (long)z * NTOK;
#pragma unroll
    for (int ti = 0; ti < 2; ++ti) {
#pragma unroll
      for (int r = 0; r < 16; ++r) {
        const long row = rowA + g.wm + ti * 32 + (r & 3) + 8 * (r >> 2) + 4 * g.half;
        float psum = 0.f;
#pragma unroll
        for (int tj = 0; tj < 2; ++tj) {
          const long col = rowB + g.wn + tj * 32 + g.l31;
          float e = __expf(acc[ti][tj][r] * 0.125f);
          bf16 eb = (bf16)e;
          C[row * (long)NTOK + col] = eb;
          psum += (float)eb;   // sum what downstream consumes
        }
#pragma unroll
        for (int off = 16; off >= 1; off >>= 1) psum += __shfl_xor(psum, off, 64);
        if (g.l31 == 0) atomicAdd(&L[row], psum);
      }
    }
  } else {
    // ---- V''-GEMM: A=Wout (1024x1024), B=V rows of QKV batch b ----
    const int v = wg - 1024;
    const int b = v >> 7, rem = v & 127;
    const int by = rem >> 4, bx = rem & 15;
    const bf16* Bm = QKV + (long)b * NTOK * QKVC + 2 * DIM;
    const long rowA = (long)by * 128;
    const long rowB = (long)bx * 128;
    GemmCore g = gemm_setup(Wout, Bm, DIM, QKVC, rowA, rowB);
    f32x16 acc[2][2] = {};
    gemm_kloop(g, DIM, As, Bs, acc);

    bf16* C = Vpp + (long)b * DIM * NTOK;
#pragma unroll
    for (int ti = 0; ti < 2; ++ti)
#pragma unroll
      for (int tj = 0; tj < 2; ++tj) {
        const long col = rowB + g.wn + tj * 32 + g.l31;
#pragma unroll
        for (int r = 0; r < 16; ++r) {
          const long row = rowA + g.wm + ti * 32 + (r & 3) + 8 * (r >> 2) + 4 * g.half;
          C[row * (long)NTOK + col] = (bf16)acc[ti][tj][r];
        }
      }
  }
}

// ---------------------------------------------------------------------------
// out_b = (E_b @ V''_b^T)/L + bias. 1D grid 512: z=wg>>7, 16(y) x 8(x).
// ---------------------------------------------------------------------------
__launch_bounds__(256)
__global__ void gemm_out(const bf16* __restrict__ Eroot, const bf16* __restrict__ Vroot,
                         float* __restrict__ Croot, const float* __restrict__ bias,
                         const float* __restrict__ Lroot) {
  __shared__ alignas(16) bf16 As[128 * 64];
  __shared__ alignas(16) bf16 Bs[128 * 64];
  int wg = blockIdx.x;
  wg = (wg & 7) * 64 + (wg >> 3);         // 512/8 = 64 per XCD, bijective
  const int z = wg >> 7, rem = wg & 127;
  const int by = rem >> 3, bx = rem & 7;

  const bf16* A  = Eroot + (long)z * NTOK * NTOK;
  const bf16* Bm = Vroot + (long)z * DIM * NTOK;
  const long rowA = (long)by * 128;
  const long rowB = (long)bx * 128;
  GemmCore g = gemm_setup(A, Bm, NTOK, NTOK, rowA, rowB);

  f32x16 acc[2][2] = {};
  gemm_kloop(g, NTOK, As, Bs, acc);

  float* C = Croot + (long)z * NTOK * DIM;
  const float* L = Lroot + (long)z * NTOK;
#pragma unroll
  for (int ti = 0; ti < 2; ++ti) {
#pragma unroll
    for (int r = 0; r < 16; ++r) {
      const long row = rowA + g.wm + ti * 32 + (r & 3) + 8 * (r >> 2) + 4 * g.half;
      const float inv = 1.0f / L[row];
#pragma unroll
      for (int tj = 0; tj < 2; ++tj) {
        const long col = rowB + g.wn + tj * 32 + g.l31;
        C[row * (long)DIM + col] = acc[ti][tj][r] * inv + bias[col];
      }
    }
  }
}

// ---------------------------------------------------------------------------
extern "C" void kernel_launch(void* const* d_in, const int* in_sizes, int n_in,
                              void* d_out, int out_size, void* d_ws, size_t ws_size,
                              hipStream_t stream) {
  const float* x      = (const float*)d_in[0];   // (4,2048,1024)
  const float* w_qkv  = (const float*)d_in[1];   // (3072,1024)
  const float* w_out  = (const float*)d_in[2];   // (1024,1024)
  const float* b_out  = (const float*)d_in[3];   // (1024,)
  float* out = (float*)d_out;                    // (4,2048,1024) fp32

  // workspace layout (bytes) — total ~120 MiB
  char* w = (char*)d_ws;
  bf16*  Xbf   = (bf16*)(w);                          // 8192*1024*2   = 16 MiB
  bf16*  Wqkvb = (bf16*)(w + 16777216);               // 3072*1024*2   =  6 MiB
  bf16*  Woutb = (bf16*)(w + 23068672);               // 1024*1024*2   =  2 MiB
  bf16*  QKV   = (bf16*)(w + 25165824);               // 8192*3072*2   = 48 MiB
  bf16*  E     = (bf16*)(w + 75497472);               // 4*2048*2048*2 = 32 MiB
  bf16*  Vpp   = (bf16*)(w + 109051904);              // 4*1024*2048*2 = 16 MiB
  float* L     = (float*)(w + 125829120);             // 4*2048*4      = 32 KiB

  // 1) one prep dispatch: converts + L zero
  {
    const int n4 = MROWS * DIM / 4 + QKVC * DIM / 4 + DIM * DIM / 4 + BATCH * NTOK / 4;
    prep<<<(n4 + 255) / 256, 256, 0, stream>>>(x, w_qkv, w_out, Xbf, Wqkvb, Woutb, L);
  }

  // 2) QKV = X @ Wqkv^T -> bf16 (8192 x 3072); 1536 blocks, XCD-swizzled
  gemm_qkv<<<1536, 256, 0, stream>>>(Xbf, Wqkvb, QKV);

  // 3) fused: E_b = exp(Q_b@K_b^T/8) + L row-sums AND V''_b = Wout @ V_b^T
  //    exact 1536 blocks (1024 E + 512 V''), XCD-swizzled
  gemm_sv<<<1536, 256, 0, stream>>>(QKV, Woutb, E, Vpp, L);

  // 4) out_b = (E_b @ V''_b^T)/L + b_out -> fp32; 512 blocks, XCD-swizzled
  gemm_out<<<512, 256, 0, stream>>>(E, Vpp, out, b_out, L);
}

// Round 7
// 272.182 us; speedup vs baseline: 1.2339x; 1.0071x over previous
//
#include <hip/hip_runtime.h>

// ---------------------------------------------------------------------------
// SelfAttentionBlock: B=4, N=2048, D=1024.
//   QKV = X @ Wqkv^T                   (8192x1024)@(3072x1024)^T   [8-phase 256²]
//   E_b = exp(Q_b @ K_b^T * 0.125)     bf16 + row-sum L (atomic)   [8-phase 256²]
//   V''_b = Wout @ V_b^T               (1024x2048) per batch       [8-phase 256², fused]
//   out_b = (E_b @ V''_b^T) / L + b    fp32                        [128² proven core]
// R14 = R13 with the vmcnt race FIXED: waits now sit immediately BEFORE a
// barrier (wait->rendezvous->read makes each wave's own-count guarantee
// collective). R13 had barrier->wait->read: W2's reads raced W1's staging
// loads (absmax 0.44). Ledger:
//   prologue: stage 8 shots, vmcnt(2), barrier  (q0 needs B all + A0/A2)
//   end q1:   vmcnt(4) [last tile: vmcnt(0)]    (q2/q3 need A1/A3 of t)
//   end q3:   vmcnt(2) (MORE only)              (next q0 needs B+A0/A2 of t+1)
// Stage order per tile: q0 B0,B1 | q1 B2,B3 | q2 A0,A2 | q3 A1,A3 -> every
// load >=2 phases flight; vmcnt never drains to 0 except last tile.
// NO sched_barrier anywhere (R2 lesson).
// ---------------------------------------------------------------------------

typedef __bf16 bf16;
typedef __attribute__((ext_vector_type(8))) __bf16 bf16x8;
typedef __attribute__((ext_vector_type(4))) __bf16 bf16x4;
typedef __attribute__((ext_vector_type(16))) float f32x16;

#define BATCH 4
#define NTOK  2048
#define DIM   1024
#define MROWS (BATCH * NTOK)   // 8192
#define QKVC  (3 * DIM)        // 3072

__device__ __forceinline__ void async16(const bf16* g, bf16* l) {
  __builtin_amdgcn_global_load_lds(
      (const __attribute__((address_space(1))) void*)g,
      (__attribute__((address_space(3))) void*)l, 16, 0, 0);
}

// ---------------------------------------------------------------------------
// prep: three fp32->bf16 converts + L zero
// ---------------------------------------------------------------------------
__device__ __forceinline__ void cvt4(const float* in, bf16* out, int i4) {
  float4 f = *(const float4*)(in + i4 * 4);
  bf16x4 o;
  o.x = (bf16)f.x; o.y = (bf16)f.y; o.z = (bf16)f.z; o.w = (bf16)f.w;
  *(bf16x4*)(out + i4 * 4) = o;
}

__global__ void prep(const float* __restrict__ x, const float* __restrict__ wqkv,
                     const float* __restrict__ wout,
                     bf16* __restrict__ Xbf, bf16* __restrict__ Wqkvb,
                     bf16* __restrict__ Woutb, float* __restrict__ L) {
  const int nx = MROWS * DIM / 4, nq = QKVC * DIM / 4, nw = DIM * DIM / 4;
  const int nl = BATCH * NTOK / 4;
  int i = blockIdx.x * blockDim.x + threadIdx.x;
  if (i < nx) cvt4(x, Xbf, i);
  else if (i < nx + nq) cvt4(wqkv, Wqkvb, i - nx);
  else if (i < nx + nq + nw) cvt4(wout, Woutb, i - nx - nq);
  else if (i < nx + nq + nw + nl) {
    float4 z = {0.f, 0.f, 0.f, 0.f};
    *(float4*)(L + (i - nx - nq - nw) * 4) = z;
  }
}

// ===========================================================================
// 8-phase 256² core. C[i][j] = sum_k A[i][k]*B[j][k], K = 1024 (16 tiles).
// 8 waves (2Mx4N), wave 128x64 = 4x2 of 32x32x16, BK=64.
// LDS [256 rows][64 k] per matrix per buf (A0|B0|A1|B1, 16384 elems each).
// Row = 8 chunks of 8 bf16; physical slot c of row r holds global chunk
// c^(r&7); swizzle on GLOBAL source col; global_load_lds dst linear (tid*16).
// Stage shot = 64 rows = 4096 elems = 512 thr x 8 elems.
// A-frag: A[m=lane&31][k=8*(lane>>5)+e]; C/D: col=lane&31,
// row=(reg&3)+8*(reg>>2)+4*(lane>>5).   [R2-verified algebra]
// ===========================================================================

template <bool MORE, bool LAST>
__device__ __forceinline__ void phase_tile(
    const bf16* Ac, const bf16* Bc, bf16* An, bf16* Bn,
    const bf16* const pA[4], const bf16* const pB[4], int ktn,
    int dst, int wr, int wc, int l31, int half, f32x16 acc[4][2]) {
  const int sw = l31 & 7;
  bf16x8 bv[2][4];
#pragma unroll
  for (int q = 0; q < 4; ++q) {
    // ds_reads: A quadrant q (4 reads); B all fragments on q==0 (8 reads)
    bf16x8 av[4];
    {
      const int arow = wr * 128 + q * 32 + l31;
#pragma unroll
      for (int k16 = 0; k16 < 4; ++k16)
        av[k16] = *(const bf16x8*)&Ac[arow * 64 + ((k16 * 2 + half) ^ sw) * 8];
    }
    if (q == 0) {
#pragma unroll
      for (int tj = 0; tj < 2; ++tj) {
        const int brow = wc * 64 + tj * 32 + l31;
#pragma unroll
        for (int k16 = 0; k16 < 4; ++k16)
          bv[tj][k16] = *(const bf16x8*)&Bc[brow * 64 + ((k16 * 2 + half) ^ sw) * 8];
      }
    }
    // stage 2 shots of tile t+1 (order B0,B1 | B2,B3 | A0,A2 | A1,A3)
    if (MORE) {
      if (q == 0) { async16(pB[0] + ktn, Bn + dst);
                    async16(pB[1] + ktn, Bn + 4096 + dst); }
      if (q == 1) { async16(pB[2] + ktn, Bn + 8192 + dst);
                    async16(pB[3] + ktn, Bn + 12288 + dst); }
      if (q == 2) { async16(pA[0] + ktn, An + dst);
                    async16(pA[2] + ktn, An + 8192 + dst); }
      if (q == 3) { async16(pA[1] + ktn, An + 4096 + dst);
                    async16(pA[3] + ktn, An + 12288 + dst); }
    }
    __builtin_amdgcn_s_barrier();                       // mid
    asm volatile("s_waitcnt lgkmcnt(0)" ::: "memory");
    __builtin_amdgcn_s_setprio(1);
#pragma unroll
    for (int k16 = 0; k16 < 4; ++k16)
#pragma unroll
      for (int tj = 0; tj < 2; ++tj)
        acc[q][tj] = __builtin_amdgcn_mfma_f32_32x32x16_bf16(
            av[k16], bv[tj][k16], acc[q][tj], 0, 0, 0);
    __builtin_amdgcn_s_setprio(0);
    // counted waits BEFORE the end barrier (collective after rendezvous):
    if (q == 1) {
      if (LAST) asm volatile("s_waitcnt vmcnt(0)" ::: "memory");
      else      asm volatile("s_waitcnt vmcnt(4)" ::: "memory");
    }
    if (q == 3 && MORE) asm volatile("s_waitcnt vmcnt(2)" ::: "memory");
    __builtin_amdgcn_s_barrier();                       // end
  }
}

// full K=1024 pipeline (16 tiles), LDS layout: A0|B0|A1|B1 (16384 elems each)
__device__ __forceinline__ void gemm8p(const bf16* __restrict__ A,
                                       const bf16* __restrict__ Bm,
                                       int lda, int ldb, long rowA, long rowB,
                                       bf16* sm, int wr, int wc, int l31, int half,
                                       f32x16 acc[4][2]) {
  const int tid = threadIdx.x;
  const int srow = tid >> 3, sc = tid & 7;
  const int scol = (sc ^ (srow & 7)) << 3;
  const int dst = tid * 8;

  const bf16* pA[4];
  const bf16* pB[4];
#pragma unroll
  for (int j = 0; j < 4; ++j) {
    pA[j] = A  + (rowA + srow + 64 * j) * (long)lda + scol;
    pB[j] = Bm + (rowB + srow + 64 * j) * (long)ldb + scol;
  }

  bf16* A0 = sm;
  bf16* B0 = sm + 16384;
  bf16* A1 = sm + 32768;
  bf16* B1 = sm + 49152;

  // prologue: stage tile 0 into buf0 (order B0..B3, A0, A2, A1, A3),
  // then vmcnt(2) BEFORE the barrier (q0 needs B all + A0/A2).
  async16(pB[0], B0 + dst);          async16(pB[1], B0 + 4096 + dst);
  async16(pB[2], B0 + 8192 + dst);   async16(pB[3], B0 + 12288 + dst);
  async16(pA[0], A0 + dst);          async16(pA[2], A0 + 8192 + dst);
  async16(pA[1], A0 + 4096 + dst);   async16(pA[3], A0 + 12288 + dst);
  asm volatile("s_waitcnt vmcnt(2)" ::: "memory");
  __builtin_amdgcn_s_barrier();

  const bf16 *Ac = A0, *Bc = B0;
  bf16 *An = A1, *Bn = B1;
#pragma unroll 1
  for (int t = 0; t < 15; ++t) {
    phase_tile<true, false>(Ac, Bc, An, Bn, pA, pB, (t + 1) * 64,
                            dst, wr, wc, l31, half, acc);
    const bf16* ta = Ac; Ac = An; An = (bf16*)ta;
    const bf16* tb = Bc; Bc = Bn; Bn = (bf16*)tb;
  }
  phase_tile<false, true>(Ac, Bc, An, Bn, pA, pB, 0,
                          dst, wr, wc, l31, half, acc);
}

// ---- QKV = X @ Wqkv^T, 256² 8-phase, bf16 out ------------------------------
__launch_bounds__(512, 2)
__global__ void g8p_qkv(const bf16* __restrict__ Xb, const bf16* __restrict__ Wq,
                        bf16* __restrict__ QKV) {
  extern __shared__ bf16 sm[];
  const int tid = threadIdx.x, wave = tid >> 6, lane = tid & 63;
  const int wr = wave >> 2, wc = wave & 3, l31 = lane & 31, half = lane >> 5;
  const int by = blockIdx.x / 12, bx = blockIdx.x % 12;
  const long rowA = (long)by * 256, rowB = (long)bx * 256;
  f32x16 acc[4][2] = {};
  gemm8p(Xb, Wq, DIM, DIM, rowA, rowB, sm, wr, wc, l31, half, acc);
#pragma unroll
  for (int ti = 0; ti < 4; ++ti)
#pragma unroll
    for (int tj = 0; tj < 2; ++tj) {
      const long col = rowB + wc * 64 + tj * 32 + l31;
#pragma unroll
      for (int r = 0; r < 16; ++r) {
        const long row = rowA + wr * 128 + ti * 32 + (r & 3) + 8 * (r >> 2) + 4 * half;
        QKV[row * (long)QKVC + col] = (bf16)acc[ti][tj][r];
      }
    }
}

// ---- fused: wg<256 -> E_b = exp(QK^T/8)+L ; else V''_b = Wout @ V_b^T ------
__launch_bounds__(512, 2)
__global__ void g8p_sv(const bf16* __restrict__ QKV, const bf16* __restrict__ Wout,
                       bf16* __restrict__ E, bf16* __restrict__ Vpp,
                       float* __restrict__ Lroot) {
  extern __shared__ bf16 sm[];
  const int tid = threadIdx.x, wave = tid >> 6, lane = tid & 63;
  const int wr = wave >> 2, wc = wave & 3, l31 = lane & 31, half = lane >> 5;
  const int wg = blockIdx.x;
  if (wg < 256) {
    // ---- E-GEMM: A=Q, B=K rows of QKV batch z; 8x8 tiles of 256 ----
    const int z = wg >> 6, rem = wg & 63;
    const int by = rem >> 3, bx = rem & 7;
    const bf16* A  = QKV + (long)z * NTOK * QKVC;
    const bf16* Bm = A + DIM;
    const long rowA = (long)by * 256, rowB = (long)bx * 256;
    f32x16 acc[4][2] = {};
    gemm8p(A, Bm, QKVC, QKVC, rowA, rowB, sm, wr, wc, l31, half, acc);

    bf16* C = E + (long)z * NTOK * NTOK;
    float* L = Lroot + (long)z * NTOK;
#pragma unroll
    for (int ti = 0; ti < 4; ++ti) {
#pragma unroll
      for (int r = 0; r < 16; ++r) {
        const long row = rowA + wr * 128 + ti * 32 + (r & 3) + 8 * (r >> 2) + 4 * half;
        float psum = 0.f;
#pragma unroll
        for (int tj = 0; tj < 2; ++tj) {
          const long col = rowB + wc * 64 + tj * 32 + l31;
          float e = __expf(acc[ti][tj][r] * 0.125f);
          bf16 eb = (bf16)e;
          C[row * (long)NTOK + col] = eb;
          psum += (float)eb;   // sum what downstream consumes
        }
#pragma unroll
        for (int off = 16; off >= 1; off >>= 1) psum += __shfl_xor(psum, off, 64);
        if (l31 == 0) atomicAdd(&L[row], psum);
      }
    }
  } else {
    // ---- V''-GEMM: A=Wout (1024x1024), B=V rows of QKV batch b; 4x8 tiles --
    const int v = wg - 256;
    const int b = v >> 5, rem = v & 31;
    const int by = rem >> 3, bx = rem & 7;
    const bf16* Bm = QKV + (long)b * NTOK * QKVC + 2 * DIM;
    const long rowA = (long)by * 256, rowB = (long)bx * 256;
    f32x16 acc[4][2] = {};
    gemm8p(Wout, Bm, DIM, QKVC, rowA, rowB, sm, wr, wc, l31, half, acc);

    bf16* C = Vpp + (long)b * DIM * NTOK;
#pragma unroll
    for (int ti = 0; ti < 4; ++ti)
#pragma unroll
      for (int tj = 0; tj < 2; ++tj) {
        const long col = rowB + wc * 64 + tj * 32 + l31;
#pragma unroll
        for (int r = 0; r < 16; ++r) {
          const long row = rowA + wr * 128 + ti * 32 + (r & 3) + 8 * (r >> 2) + 4 * half;
          C[row * (long)NTOK + col] = (bf16)acc[ti][tj][r];
        }
      }
  }
}

// ===========================================================================
// 128² proven core for the out-GEMM (512 blocks; 256² would half-fill).
// ===========================================================================
struct GemmCore {
  const bf16 *ga[4], *gb[4];
  int sIdx[4];
  int wm, wn, l31, half;
};

__device__ __forceinline__ GemmCore gemm_setup(const bf16* A, const bf16* Bm,
                                               int lda, int ldb,
                                               long rowA, long rowB) {
  GemmCore g;
  const int tid = threadIdx.x;
  const int wave = tid >> 6, lane = tid & 63;
  g.wm = (wave >> 1) << 6;
  g.wn = (wave & 1) << 6;
  g.l31 = lane & 31;
  g.half = lane >> 5;
  const int srow = tid >> 3;
  const int sc   = tid & 7;
  const int scol = (sc ^ (srow & 7)) << 3;
#pragma unroll
  for (int seg = 0; seg < 4; ++seg) {
    g.ga[seg] = A  + (rowA + srow + 32 * seg) * (long)lda + scol;
    g.gb[seg] = Bm + (rowB + srow + 32 * seg) * (long)ldb + scol;
    g.sIdx[seg] = (srow + 32 * seg) * 64 + sc * 8;
  }
  return g;
}

__device__ __forceinline__ void gemm_kloop(const GemmCore& g, int K,
                                           bf16* As, bf16* Bs, f32x16 acc[2][2]) {
  const int sw = g.l31 & 7;
  for (int kt = 0; kt < K; kt += 64) {
#pragma unroll
    for (int seg = 0; seg < 4; ++seg) {
      async16(g.ga[seg] + kt, As + g.sIdx[seg]);
      async16(g.gb[seg] + kt, Bs + g.sIdx[seg]);
    }
    __syncthreads();

    bf16x8 af[2][4], bfm[2][4];
#pragma unroll
    for (int ti = 0; ti < 2; ++ti)
#pragma unroll
      for (int s = 0; s < 4; ++s)
        af[ti][s] = *(const bf16x8*)&As[(g.wm + ti * 32 + g.l31) * 64 + ((s * 2 + g.half) ^ sw) * 8];
#pragma unroll
    for (int tj = 0; tj < 2; ++tj)
#pragma unroll
      for (int s = 0; s < 4; ++s)
        bfm[tj][s] = *(const bf16x8*)&Bs[(g.wn + tj * 32 + g.l31) * 64 + ((s * 2 + g.half) ^ sw) * 8];

#pragma unroll
    for (int s = 0; s < 4; ++s)
#pragma unroll
      for (int ti = 0; ti < 2; ++ti)
#pragma unroll
        for (int tj = 0; tj < 2; ++tj)
          acc[ti][tj] = __builtin_amdgcn_mfma_f32_32x32x16_bf16(
              af[ti][s], bfm[tj][s], acc[ti][tj], 0, 0, 0);

    __syncthreads();
  }
}

// out_b = (E_b @ V''_b^T)/L + bias. 1D grid 512: z=wg>>7, 16(y) x 8(x).
__launch_bounds__(256)
__global__ void gemm_out(const bf16* __restrict__ Eroot, const bf16* __restrict__ Vroot,
                         float* __restrict__ Croot, const float* __restrict__ bias,
                         const float* __restrict__ Lroot) {
  __shared__ alignas(16) bf16 As[128 * 64];
  __shared__ alignas(16) bf16 Bs[128 * 64];
  int wg = blockIdx.x;
  wg = (wg & 7) * 64 + (wg >> 3);         // 512/8 = 64 per XCD, bijective
  const int z = wg >> 7, rem = wg & 127;
  const int by = rem >> 3, bx = rem & 7;

  const bf16* A  = Eroot + (long)z * NTOK * NTOK;
  const bf16* Bm = Vroot + (long)z * DIM * NTOK;
  const long rowA = (long)by * 128;
  const long rowB = (long)bx * 128;
  GemmCore g = gemm_setup(A, Bm, NTOK, NTOK, rowA, rowB);

  f32x16 acc[2][2] = {};
  gemm_kloop(g, NTOK, As, Bs, acc);

  float* C = Croot + (long)z * NTOK * DIM;
  const float* L = Lroot + (long)z * NTOK;
#pragma unroll
  for (int ti = 0; ti < 2; ++ti) {
#pragma unroll
    for (int r = 0; r < 16; ++r) {
      const long row = rowA + g.wm + ti * 32 + (r & 3) + 8 * (r >> 2) + 4 * g.half;
      const float inv = 1.0f / L[row];
#pragma unroll
      for (int tj = 0; tj < 2; ++tj) {
        const long col = rowB + g.wn + tj * 32 + g.l31;
        C[row * (long)DIM + col] = acc[ti][tj][r] * inv + bias[col];
      }
    }
  }
}

// ---------------------------------------------------------------------------
extern "C" void kernel_launch(void* const* d_in, const int* in_sizes, int n_in,
                              void* d_out, int out_size, void* d_ws, size_t ws_size,
                              hipStream_t stream) {
  const float* x      = (const float*)d_in[0];   // (4,2048,1024)
  const float* w_qkv  = (const float*)d_in[1];   // (3072,1024)
  const float* w_out  = (const float*)d_in[2];   // (1024,1024)
  const float* b_out  = (const float*)d_in[3];   // (1024,)
  float* out = (float*)d_out;                    // (4,2048,1024) fp32

  // workspace layout (bytes) — total ~120 MiB
  char* w = (char*)d_ws;
  bf16*  Xbf   = (bf16*)(w);                          // 8192*1024*2   = 16 MiB
  bf16*  Wqkvb = (bf16*)(w + 16777216);               // 3072*1024*2   =  6 MiB
  bf16*  Woutb = (bf16*)(w + 23068672);               // 1024*1024*2   =  2 MiB
  bf16*  QKV   = (bf16*)(w + 25165824);               // 8192*3072*2   = 48 MiB
  bf16*  E     = (bf16*)(w + 75497472);               // 4*2048*2048*2 = 32 MiB
  bf16*  Vpp   = (bf16*)(w + 109051904);              // 4*1024*2048*2 = 16 MiB
  float* L     = (float*)(w + 125829120);             // 4*2048*4      = 32 KiB

  // 1) one prep dispatch: converts + L zero
  {
    const int n4 = MROWS * DIM / 4 + QKVC * DIM / 4 + DIM * DIM / 4 + BATCH * NTOK / 4;
    prep<<<(n4 + 255) / 256, 256, 0, stream>>>(x, w_qkv, w_out, Xbf, Wqkvb, Woutb, L);
  }

  // 2) QKV = X @ Wqkv^T -> bf16 (8192 x 3072); 32x12 = 384 blocks, 8-phase
  g8p_qkv<<<384, 512, 131072, stream>>>(Xbf, Wqkvb, QKV);

  // 3) fused: E (256 blocks) + V'' (128 blocks) = 384 blocks, 8-phase
  g8p_sv<<<384, 512, 131072, stream>>>(QKV, Woutb, E, Vpp, L);

  // 4) out_b = (E_b @ V''_b^T)/L + b_out -> fp32; 512 blocks, 128² core
  gemm_out<<<512, 256, 0, stream>>>(E, Vpp, out, b_out, L);
}

// Round 8
// 270.750 us; speedup vs baseline: 1.2404x; 1.0053x over previous
//
#include <hip/hip_runtime.h>

// ---------------------------------------------------------------------------
// SelfAttentionBlock: B=4, N=2048, D=1024. Single-head attention, head dim 1024.
//   QKV = X @ Wqkv^T                   (8192x1024)@(3072x1024)^T
//   E_b = exp(Q_b @ K_b^T * 0.125)     bf16, fused epilogue, row sums L (atomic)
//   V''_b = Wout @ V_b^T               (1024x2048) per batch
//   out_b = (E_b @ V''_b^T) / L + b    fp32
// R15: BK=128 on the proven R1 1-phase core. Halves the K-tile count ->
// halves full-block rendezvous (the only untried axis after R2/R3/R5/R7
// schedule interventions all landed at MfmaUtil 25-29%). LDS 64 KiB single
// buffer -> still 2 blocks/CU (R1 measures ~2 effective at 32 KiB; m132's
// BK=128 regression was a 3->2 block drop we don't have). Row pitch 256 B,
// 16 chunk slots, swizzle c^(r&15): 32 lanes over 16 slots = 2-way aliasing
// (free, m136) vs BK=64's 4-lane/slot. K-order unchanged -> bit-identical.
// ---------------------------------------------------------------------------

typedef __bf16 bf16;
typedef __attribute__((ext_vector_type(8))) __bf16 bf16x8;
typedef __attribute__((ext_vector_type(4))) __bf16 bf16x4;
typedef __attribute__((ext_vector_type(16))) float f32x16;

#define BATCH 4
#define NTOK  2048
#define DIM   1024
#define MROWS (BATCH * NTOK)   // 8192
#define QKVC  (3 * DIM)        // 3072

__device__ __forceinline__ void async16(const bf16* g, bf16* l) {
  __builtin_amdgcn_global_load_lds(
      (const __attribute__((address_space(1))) void*)g,
      (__attribute__((address_space(3))) void*)l, 16, 0, 0);
}

// ---------------------------------------------------------------------------
// one prep kernel: three fp32->bf16 converts + L zero
// ---------------------------------------------------------------------------
__device__ __forceinline__ void cvt4(const float* in, bf16* out, int i4) {
  float4 f = *(const float4*)(in + i4 * 4);
  bf16x4 o;
  o.x = (bf16)f.x; o.y = (bf16)f.y; o.z = (bf16)f.z; o.w = (bf16)f.w;
  *(bf16x4*)(out + i4 * 4) = o;
}

__global__ void prep(const float* __restrict__ x, const float* __restrict__ wqkv,
                     const float* __restrict__ wout,
                     bf16* __restrict__ Xbf, bf16* __restrict__ Wqkvb,
                     bf16* __restrict__ Woutb, float* __restrict__ L) {
  const int nx = MROWS * DIM / 4, nq = QKVC * DIM / 4, nw = DIM * DIM / 4;
  const int nl = BATCH * NTOK / 4;
  int i = blockIdx.x * blockDim.x + threadIdx.x;
  if (i < nx) cvt4(x, Xbf, i);
  else if (i < nx + nq) cvt4(wqkv, Wqkvb, i - nx);
  else if (i < nx + nq + nw) cvt4(wout, Woutb, i - nx - nq);
  else if (i < nx + nq + nw + nl) {
    float4 z = {0.f, 0.f, 0.f, 0.f};
    *(float4*)(L + (i - nx - nq - nw) * 4) = z;
  }
}

// ---------------------------------------------------------------------------
// GEMM core, BK=128. C[i][j] = sum_k A[i][k] * B[j][k] (B^T pattern).
// 32x32x16 MFMA, 4 waves 2x2, wave 64x64 = 2x2 of 32x32.
// A-frag: A[m=lane&31][k=8*(lane>>5)+e]. C/D: col=lane&31,
// row=(reg&3)+8*(reg>>2)+4*(lane>>5).
// LDS tile [128 rows][128 k] = 32 KB/matrix, 256B rows = 16 chunks of 8 bf16;
// physical slot c of row r holds global chunk c^(r&15). Staging: shot =
// 256 thr x 16 B = 16 rows; srow=tid>>4, sc=tid&15, 8 shots (seg) per matrix;
// global source col pre-swizzled so LDS dst stays linear (tid*16 B).
// Read: row = wm+ti*32+l31 -> row&15 == l31&15; k-chunk g = ks*2+half
// (ks 0..7) -> slot g^(l31&15). 32 lanes / 16 slots = 2-way (free).
// ---------------------------------------------------------------------------
struct GemmCore {
  const bf16 *ga[8], *gb[8];
  int sIdx[8];
  int wm, wn, l31, half;
};

__device__ __forceinline__ GemmCore gemm_setup(const bf16* A, const bf16* Bm,
                                               int lda, int ldb,
                                               long rowA, long rowB) {
  GemmCore g;
  const int tid = threadIdx.x;
  const int wave = tid >> 6, lane = tid & 63;
  g.wm = (wave >> 1) << 6;
  g.wn = (wave & 1) << 6;
  g.l31 = lane & 31;
  g.half = lane >> 5;
  const int srow = tid >> 4;               // 0..15
  const int sc   = tid & 15;               // physical slot
  const int scol = (sc ^ srow) << 3;       // swizzled global chunk * 8
#pragma unroll
  for (int seg = 0; seg < 8; ++seg) {
    g.ga[seg] = A  + (rowA + srow + 16 * seg) * (long)lda + scol;
    g.gb[seg] = Bm + (rowB + srow + 16 * seg) * (long)ldb + scol;
    g.sIdx[seg] = (srow + 16 * seg) * 128 + sc * 8;
  }
  return g;
}

__device__ __forceinline__ void gemm_kloop(const GemmCore& g, int K,
                                           bf16* As, bf16* Bs, f32x16 acc[2][2]) {
  const int sw = g.l31 & 15;
  for (int kt = 0; kt < K; kt += 128) {
#pragma unroll
    for (int seg = 0; seg < 8; ++seg) {
      async16(g.ga[seg] + kt, As + g.sIdx[seg]);
      async16(g.gb[seg] + kt, Bs + g.sIdx[seg]);
    }
    __syncthreads();

#pragma unroll
    for (int ks = 0; ks < 8; ++ks) {
      bf16x8 af[2], bfm[2];
      const int slot = ((ks * 2 + g.half) ^ sw) * 8;
#pragma unroll
      for (int ti = 0; ti < 2; ++ti)
        af[ti] = *(const bf16x8*)&As[(g.wm + ti * 32 + g.l31) * 128 + slot];
#pragma unroll
      for (int tj = 0; tj < 2; ++tj)
        bfm[tj] = *(const bf16x8*)&Bs[(g.wn + tj * 32 + g.l31) * 128 + slot];
#pragma unroll
      for (int ti = 0; ti < 2; ++ti)
#pragma unroll
        for (int tj = 0; tj < 2; ++tj)
          acc[ti][tj] = __builtin_amdgcn_mfma_f32_32x32x16_bf16(
              af[ti], bfm[tj], acc[ti][tj], 0, 0, 0);
    }

    __syncthreads();
  }
}

// ---------------------------------------------------------------------------
// Plain GEMMs. MODE 0: store bf16. MODE 2: store fp32 v/L[row] + bias[col].
// ---------------------------------------------------------------------------
template <int MODE>
__launch_bounds__(256)
__global__ void gemm_bt(const bf16* __restrict__ Aroot, const bf16* __restrict__ Broot,
                        void* __restrict__ Croot, const float* __restrict__ bias,
                        const float* __restrict__ Lroot,
                        int K, int lda, int ldb, int ldc,
                        long strideA, long strideB, long strideC) {
  const bf16* A  = Aroot + (long)blockIdx.z * strideA;
  const bf16* Bm = Broot + (long)blockIdx.z * strideB;
  __shared__ alignas(16) bf16 As[128 * 128];
  __shared__ alignas(16) bf16 Bs[128 * 128];

  const long rowA = (long)blockIdx.y * 128;
  const long rowB = (long)blockIdx.x * 128;
  GemmCore g = gemm_setup(A, Bm, lda, ldb, rowA, rowB);

  f32x16 acc[2][2] = {};
  gemm_kloop(g, K, As, Bs, acc);

  if constexpr (MODE == 0) {
    bf16* C = (bf16*)Croot + (long)blockIdx.z * strideC;
#pragma unroll
    for (int ti = 0; ti < 2; ++ti)
#pragma unroll
      for (int tj = 0; tj < 2; ++tj) {
        const long col = rowB + g.wn + tj * 32 + g.l31;
#pragma unroll
        for (int r = 0; r < 16; ++r) {
          const long row = rowA + g.wm + ti * 32 + (r & 3) + 8 * (r >> 2) + 4 * g.half;
          C[row * (long)ldc + col] = (bf16)acc[ti][tj][r];
        }
      }
  } else {
    float* C = (float*)Croot + (long)blockIdx.z * strideC;
    const float* L = Lroot + (long)blockIdx.z * NTOK;
#pragma unroll
    for (int ti = 0; ti < 2; ++ti) {
#pragma unroll
      for (int r = 0; r < 16; ++r) {
        const long row = rowA + g.wm + ti * 32 + (r & 3) + 8 * (r >> 2) + 4 * g.half;
        const float inv = 1.0f / L[row];
#pragma unroll
        for (int tj = 0; tj < 2; ++tj) {
          const long col = rowB + g.wn + tj * 32 + g.l31;
          C[row * (long)ldc + col] = acc[ti][tj][r] * inv + bias[col];
        }
      }
    }
  }
}

// ---------------------------------------------------------------------------
// Fused dispatch: z<4 -> E_b = exp(Q_b@K_b^T/8) + row-sum L (batch z);
//                 z>=4 -> V''_b = Wout @ V_b^T (batch z-4; blockIdx.y>=8 idle).
// ---------------------------------------------------------------------------
__launch_bounds__(256)
__global__ void gemm_sv(const bf16* __restrict__ QKV, const bf16* __restrict__ Wout,
                        bf16* __restrict__ E, bf16* __restrict__ Vpp,
                        float* __restrict__ Lroot) {
  __shared__ alignas(16) bf16 As[128 * 128];
  __shared__ alignas(16) bf16 Bs[128 * 128];

  const int z = blockIdx.z;
  if (z < 4) {
    // ---- E-GEMM: A=Q, B=K rows of QKV batch z ----
    const bf16* A  = QKV + (long)z * NTOK * QKVC;
    const bf16* Bm = A + DIM;
    const long rowA = (long)blockIdx.y * 128;
    const long rowB = (long)blockIdx.x * 128;
    GemmCore g = gemm_setup(A, Bm, QKVC, QKVC, rowA, rowB);
    f32x16 acc[2][2] = {};
    gemm_kloop(g, DIM, As, Bs, acc);

    bf16* C = E + (long)z * NTOK * NTOK;
    float* L = Lroot + (long)z * NTOK;
#pragma unroll
    for (int ti = 0; ti < 2; ++ti) {
#pragma unroll
      for (int r = 0; r < 16; ++r) {
        const long row = rowA + g.wm + ti * 32 + (r & 3) + 8 * (r >> 2) + 4 * g.half;
        float psum = 0.f;
#pragma unroll
        for (int tj = 0; tj < 2; ++tj) {
          const long col = rowB + g.wn + tj * 32 + g.l31;
          float e = __expf(acc[ti][tj][r] * 0.125f);
          bf16 eb = (bf16)e;
          C[row * (long)NTOK + col] = eb;
          psum += (float)eb;   // sum what downstream consumes
        }
#pragma unroll
        for (int off = 16; off >= 1; off >>= 1) psum += __shfl_xor(psum, off, 64);
        if (g.l31 == 0) atomicAdd(&L[row], psum);
      }
    }
  } else {
    if (blockIdx.y >= 8) return;   // V'' output is 1024 rows = 8 row-tiles
    // ---- V''-GEMM: A=Wout (1024x1024), B=V rows of QKV batch z-4 ----
    const int b = z - 4;
    const bf16* Bm = QKV + (long)b * NTOK * QKVC + 2 * DIM;
    const long rowA = (long)blockIdx.y * 128;
    const long rowB = (long)blockIdx.x * 128;
    GemmCore g = gemm_setup(Wout, Bm, DIM, QKVC, rowA, rowB);
    f32x16 acc[2][2] = {};
    gemm_kloop(g, DIM, As, Bs, acc);

    bf16* C = Vpp + (long)b * DIM * NTOK;
#pragma unroll
    for (int ti = 0; ti < 2; ++ti)
#pragma unroll
      for (int tj = 0; tj < 2; ++tj) {
        const long col = rowB + g.wn + tj * 32 + g.l31;
#pragma unroll
        for (int r = 0; r < 16; ++r) {
          const long row = rowA + g.wm + ti * 32 + (r & 3) + 8 * (r >> 2) + 4 * g.half;
          C[row * (long)NTOK + col] = (bf16)acc[ti][tj][r];
        }
      }
  }
}

// ---------------------------------------------------------------------------
extern "C" void kernel_launch(void* const* d_in, const int* in_sizes, int n_in,
                              void* d_out, int out_size, void* d_ws, size_t ws_size,
                              hipStream_t stream) {
  const float* x      = (const float*)d_in[0];   // (4,2048,1024)
  const float* w_qkv  = (const float*)d_in[1];   // (3072,1024)
  const float* w_out  = (const float*)d_in[2];   // (1024,1024)
  const float* b_out  = (const float*)d_in[3];   // (1024,)
  float* out = (float*)d_out;                    // (4,2048,1024) fp32

  // workspace layout (bytes) — total ~120 MiB
  char* w = (char*)d_ws;
  bf16*  Xbf   = (bf16*)(w);                          // 8192*1024*2   = 16 MiB
  bf16*  Wqkvb = (bf16*)(w + 16777216);               // 3072*1024*2   =  6 MiB
  bf16*  Woutb = (bf16*)(w + 23068672);               // 1024*1024*2   =  2 MiB
  bf16*  QKV   = (bf16*)(w + 25165824);               // 8192*3072*2   = 48 MiB
  bf16*  E     = (bf16*)(w + 75497472);               // 4*2048*2048*2 = 32 MiB
  bf16*  Vpp   = (bf16*)(w + 109051904);              // 4*1024*2048*2 = 16 MiB
  float* L     = (float*)(w + 125829120);             // 4*2048*4      = 32 KiB

  // 1) one prep dispatch: converts + L zero
  {
    const int n4 = MROWS * DIM / 4 + QKVC * DIM / 4 + DIM * DIM / 4 + BATCH * NTOK / 4;
    prep<<<(n4 + 255) / 256, 256, 0, stream>>>(x, w_qkv, w_out, Xbf, Wqkvb, Woutb, L);
  }

  // 2) QKV = X @ Wqkv^T -> bf16 (8192 x 3072)
  gemm_bt<0><<<dim3(QKVC / 128, MROWS / 128, 1), 256, 0, stream>>>(
      Xbf, Wqkvb, QKV, nullptr, nullptr, DIM, DIM, DIM, QKVC, 0, 0, 0);

  // 3) fused: E_b = exp(Q_b@K_b^T/8) + L row-sums  AND  V''_b = Wout @ V_b^T
  gemm_sv<<<dim3(NTOK / 128, NTOK / 128, 2 * BATCH), 256, 0, stream>>>(
      QKV, Woutb, E, Vpp, L);

  // 4) out_b = (E_b @ V''_b^T) / L + b_out -> fp32 (2048 x 1024 per batch)
  gemm_bt<2><<<dim3(DIM / 128, NTOK / 128, BATCH), 256, 0, stream>>>(
      E, Vpp, out, b_out, L, NTOK, NTOK, NTOK, DIM,
      (long)NTOK * NTOK, (long)DIM * NTOK, (long)NTOK * DIM);
}